// Round 9
// baseline (4750.925 us; speedup 1.0000x reference)
//
#include <hip/hip_runtime.h>

constexpr int T  = 1024;
constexpr int B  = 32;
constexpr int I_ = 64;
constexpr int H  = 1024;
constexpr int OF = 64;
constexpr int OC = 8;
constexpr int NG = 8;    // groups, 4 batches each (2 pairs)
constexpr int NM = 32;   // member WGs per group, 32 rows each
constexpr long long OUT1_OFF = (long long)T * B * OF;
constexpr long long OUT2_OFF = (long long)T * B * (OF + OC);
constexpr int EXCH_F32 = NG * 2 * 2 * 2048;   // [g][pair][slot][k*2+b] = 256KB

// Agent-scope relaxed ops (global_{load,store} sc0 sc1): bypass L1/L2, meet at
// the L3 coherence point, no cache-flush instructions. R2/R8-proven medium.
// (R4/R5/R7: sc0-only polling livelocks — never used here.)
__device__ __forceinline__ void st_agent_f32(float* p, float v) {
  __hip_atomic_store(p, v, __ATOMIC_RELAXED, __HIP_MEMORY_SCOPE_AGENT);
}
__device__ __forceinline__ void st_agent_u32(unsigned* p, unsigned v) {
  __hip_atomic_store(p, v, __ATOMIC_RELAXED, __HIP_MEMORY_SCOPE_AGENT);
}
__device__ __forceinline__ unsigned ld_agent_u32(const unsigned* p) {
  return __hip_atomic_load(p, __ATOMIC_RELAXED, __HIP_MEMORY_SCOPE_AGENT);
}
__device__ __forceinline__ unsigned long long
ld_agent_u64(const unsigned long long* p) {
  return __hip_atomic_load(p, __ATOMIC_RELAXED, __HIP_MEMORY_SCOPE_AGENT);
}

// ---------------------------------------------------------------------------
// Recurrence: 256 persistent WGs x 1024 threads (1/CU, 16 waves).
// Group g = bid&7 owns batches [4g,4g+4) as two pairs P0={0,1}, P1={2,3}.
// Member m = bid>>3 owns rows [m*32, m*32+32).
// Thread (r=tid>>5, s=tid&31): row j=m*32+r, k-slice {q*32+s} -> 34 weights
// per thread (fits arch-VGPR budget at the declared 4-waves/EU occupancy; no
// AGPR shuffling — R8's hidden 2x VALU tax).
// State LDS [pair][slot][k*2+b]; ds_read_b64 feeds both batches (broadcast
// pairs across half-waves, conflict-free).
//
// ALTERNATING PIPELINE (per iteration t):
//   1. compute P0(t)   -> agent-store packets -> sync(drain) -> flag0 = t+1
//   2. poll flag1>=t   -> bulk-load r^{P1}_{t-1} + x_t -> LDS   (RT hidden
//      under phase 4(t-1) + phase 1(t))
//   3. compute P1(t)   -> packets -> sync -> flag1 = t+1
//   4. poll flag0>=t+1 -> bulk-load r^{P0}_t + x_{t+1} -> LDS   (RT hidden
//      under phases 2+3)
// Liveness: flags monotone, written unconditionally after WG-local work only;
// polls are the only waits => deadlock-free by induction. Flags zeroed every
// call (graph-replay safe). Slot reuse safe: writer of exch[P][s] at iter t
// passed its iter-(t-1) poll, which proves all members consumed slot s at
// iter t-2 (their flag >= t implies they finished phase using slot s).
// ---------------------------------------------------------------------------
__global__ __launch_bounds__(1024, 4) void rnn_recur(
    const float* __restrict__ input_sig, const float* __restrict__ rate0,
    const float* __restrict__ i2h_w, const float* __restrict__ i2h_b,
    const float* __restrict__ h2h_w, const float* __restrict__ h2h_b,
    float* __restrict__ rate_all, float* __restrict__ exch,
    unsigned* __restrict__ flags)
{
  const int tid = threadIdx.x;
  const int bid = blockIdx.x;
  const int g   = bid & (NG - 1);
  const int m   = bid >> 3;
  const int r   = tid >> 5;
  const int s   = tid & 31;
  const int j   = m * 32 + r;
  const int bG  = g * 4;

  __shared__ float r_lds[2][2][2176];   // [pair][slot][k*2+b], 34.8KB

  // ---- register-stationary weights: 34 fp32/thread (row j, k=q*32+s)
  float w[34];
#pragma unroll
  for (int q = 0; q < 34; ++q) {
    const int k = q * 32 + s;
    w[q] = (k < H) ? h2h_w[(long long)j * H + k]
                   : i2h_w[(long long)j * I_ + (k - H)];
  }
  const float bsum = h2h_b[j] + i2h_b[j];

  // ---- init slot 0 for both pairs: r_{-1} = rate0, x_0
#pragma unroll
  for (int p = 0; p < 2; ++p) {
    const float v0 = rate0[(long long)(bG + 2 * p) * H + tid];
    const float v1 = rate0[(long long)(bG + 2 * p + 1) * H + tid];
    *(float2*)&r_lds[p][0][2 * tid] = make_float2(v0, v1);
  }
  if (tid < 128) {
    const int xb = tid >> 6, xi = tid & 63;
#pragma unroll
    for (int p = 0; p < 2; ++p) {
      r_lds[p][0][(1024 + xi) * 2 + xb] =
          input_sig[(long long)(bG + 2 * p + xb) * I_ + xi];
    }
  }
  __syncthreads();

  float* exG = exch + g * (2 * 2 * 2048);
  unsigned* fl0 = flags + 0 * (NG * NM) + g * NM;
  unsigned* fl1 = flags + 1 * (NG * NM) + g * NM;

  // compute pair p from LDS[p][slot_r], emit packets into exch slot_w
  auto compute_pair = [&](int p, int slot_r, int slot_w, int t) {
    const float* Rb = &r_lds[p][slot_r][0];
    float a0 = 0.f, a1 = 0.f;
#pragma unroll
    for (int q = 0; q < 34; ++q) {
      const float2 v = *(const float2*)&Rb[q * 64 + 2 * s];
      a0 = fmaf(w[q], v.x, a0);
      a1 = fmaf(w[q], v.y, a1);
    }
    // fold the two batches into lane halves of the 32-lane s-group
    const float t0 = __shfl_xor(a0, 16), t1 = __shfl_xor(a1, 16);
    float u = (s < 16) ? (a0 + t0) : (a1 + t1);
#pragma unroll
    for (int off = 8; off >= 1; off >>= 1) u += __shfl_xor(u, off);
    // producers: s==0 (batch 0), s==16 (batch 1)
    if ((s & 15) == 0) {
      const int b = s >> 4;
      const float pre  = u + bsum;
      const float rold = Rb[j * 2 + b];
      const float rnew = 0.9f * rold + 0.1f * tanhf(pre);
      st_agent_f32(&exG[(p * 2 + slot_w) * 2048 + j * 2 + b], rnew);
      rate_all[((long long)t * B + bG + 2 * p + b) * H + j] = rnew;  // plain
    }
  };

  for (int t = 0; t < T; ++t) {
    const int cur = t & 1, nxt = cur ^ 1;

    // ---- phase 1: compute P0(t), publish
    compute_pair(0, cur, nxt, t);
    __syncthreads();                 // drains packet stores (vmcnt 0)
    if (tid == 0) st_agent_u32(&fl0[m], (unsigned)(t + 1));

    // ---- phase 2: restage P1 (r_{t-1} from exch slot cur, x_t)
    if (t > 0) {
      if (tid < NM) {
        const unsigned* f = &fl1[tid];
        unsigned v;
        do { v = ld_agent_u32(f); } while (v < (unsigned)t);
      }
      __syncthreads();
      const unsigned long long v = ld_agent_u64(
          (const unsigned long long*)(exG + (1 * 2 + cur) * 2048) + tid);
      float xv; int xb = 0, xi = 0;
      const bool xs = (tid < 128);
      if (xs) {
        xb = tid >> 6; xi = tid & 63;
        xv = input_sig[((long long)t * B + bG + 2 + xb) * I_ + xi];
      }
      *(float2*)&r_lds[1][cur][2 * tid] = make_float2(
          __uint_as_float((unsigned)v), __uint_as_float((unsigned)(v >> 32)));
      if (xs) r_lds[1][cur][(1024 + xi) * 2 + xb] = xv;
      __syncthreads();
    }

    // ---- phase 3: compute P1(t), publish
    compute_pair(1, cur, nxt, t);
    __syncthreads();
    if (tid == 0) st_agent_u32(&fl1[m], (unsigned)(t + 1));

    // ---- phase 4: restage P0 (r_t from exch slot nxt, x_{t+1})
    if (t + 1 < T) {
      if (tid < NM) {
        const unsigned* f = &fl0[tid];
        unsigned v;
        do { v = ld_agent_u32(f); } while (v < (unsigned)(t + 1));
      }
      __syncthreads();
      const unsigned long long v = ld_agent_u64(
          (const unsigned long long*)(exG + (0 * 2 + nxt) * 2048) + tid);
      float xv; int xb = 0, xi = 0;
      const bool xs = (tid < 128);
      if (xs) {
        xb = tid >> 6; xi = tid & 63;
        xv = input_sig[((long long)(t + 1) * B + bG + xb) * I_ + xi];
      }
      *(float2*)&r_lds[0][nxt][2 * tid] = make_float2(
          __uint_as_float((unsigned)v), __uint_as_float((unsigned)(v >> 32)));
      if (xs) r_lds[0][nxt][(1024 + xi) * 2 + xb] = xv;
      __syncthreads();
    }
  }
}

// ---------------------------------------------------------------------------
// Readout: C[32768,72] = rate_all[32768,1024] x [h2o_w;h2o_ctx_w]^T + bias
// ---------------------------------------------------------------------------
__global__ __launch_bounds__(256) void rnn_readout(
    const float* __restrict__ rate_all,
    const float* __restrict__ h2o_w, const float* __restrict__ h2o_b,
    const float* __restrict__ h2o_ctx_w, const float* __restrict__ h2o_ctx_b,
    float* __restrict__ out0, float* __restrict__ out1)
{
  constexpr int RB = 128;
  constexpr int HC = 128;
  constexpr int SR = HC + 1;
  __shared__ float rl[RB * SR];
  __shared__ float wl[72 * SR];

  const int tid = threadIdx.x;
  const long long row0 = (long long)blockIdx.x * RB;
  const int rb = tid & 31, og = tid >> 5;

  float acc[4][9];
#pragma unroll
  for (int c = 0; c < 4; ++c)
#pragma unroll
    for (int i = 0; i < 9; ++i) acc[c][i] = 0.f;

  for (int hc = 0; hc < H / HC; ++hc) {
#pragma unroll
    for (int i = 0; i < 16; ++i) {
      const int q = i * 256 + tid;
      const int row = q >> 5, hq = q & 31;
      float4 v = *(const float4*)(rate_all + (row0 + row) * H + hc * HC + hq * 4);
      float* d = &rl[row * SR + hq * 4];
      d[0] = v.x; d[1] = v.y; d[2] = v.z; d[3] = v.w;
    }
#pragma unroll
    for (int i = 0; i < 9; ++i) {
      const int q = i * 256 + tid;
      const int o = q >> 5, hq = q & 31;
      const float* src = (o < OF) ? (h2o_w + (long long)o * H)
                                  : (h2o_ctx_w + (long long)(o - OF) * H);
      float4 v = *(const float4*)(src + hc * HC + hq * 4);
      float* d = &wl[o * SR + hq * 4];
      d[0] = v.x; d[1] = v.y; d[2] = v.z; d[3] = v.w;
    }
    __syncthreads();

#pragma unroll 4
    for (int h = 0; h < HC; ++h) {
      const float r0 = rl[(rb)      * SR + h];
      const float r1 = rl[(rb + 32) * SR + h];
      const float r2 = rl[(rb + 64) * SR + h];
      const float r3 = rl[(rb + 96) * SR + h];
#pragma unroll
      for (int i = 0; i < 9; ++i) {
        const float wv = wl[(og * 9 + i) * SR + h];
        acc[0][i] = fmaf(r0, wv, acc[0][i]);
        acc[1][i] = fmaf(r1, wv, acc[1][i]);
        acc[2][i] = fmaf(r2, wv, acc[2][i]);
        acc[3][i] = fmaf(r3, wv, acc[3][i]);
      }
    }
    __syncthreads();
  }

#pragma unroll
  for (int c = 0; c < 4; ++c) {
    const long long row = row0 + rb + 32 * c;
#pragma unroll
    for (int i = 0; i < 9; ++i) {
      const int o = og * 9 + i;
      if (o < OF) out0[row * OF + o] = acc[c][i] + h2o_b[o];
      else        out1[row * OC + (o - OF)] = acc[c][i] + h2o_ctx_b[o - OF];
    }
  }
}

extern "C" void kernel_launch(void* const* d_in, const int* in_sizes, int n_in,
                              void* d_out, int out_size, void* d_ws, size_t ws_size,
                              hipStream_t stream) {
  (void)in_sizes; (void)n_in; (void)d_ws; (void)ws_size; (void)out_size;
  const float* input_sig = (const float*)d_in[0];
  const float* rate0     = (const float*)d_in[1];
  const float* i2h_w     = (const float*)d_in[2];
  const float* i2h_b     = (const float*)d_in[3];
  const float* h2h_w     = (const float*)d_in[4];
  const float* h2h_b     = (const float*)d_in[5];
  const float* h2o_w     = (const float*)d_in[6];
  const float* h2o_b     = (const float*)d_in[7];
  const float* h2o_ctx_w = (const float*)d_in[8];
  const float* h2o_ctx_b = (const float*)d_in[9];

  float* out      = (float*)d_out;
  float* out0     = out;
  float* out1     = out + OUT1_OFF;
  float* rate_all = out + OUT2_OFF;

  // Scratch in the head of out0 (overwritten by rnn_readout afterwards):
  //   [0, 256KB)          exch: [g][pair][slot][k*2+b] f32
  //   [256KB, 256KB+2KB)  flags: [pair][g][m] u32 (monotone step counters)
  float*    exch  = out0;
  unsigned* flags = (unsigned*)(out0 + EXCH_F32);

  // Zero flags EVERY call: a stale (previous-call) flag would short-circuit
  // the polls and expose stale exch data. exch itself is gated by flags and
  // always written this call, so it needs no re-init.
  hipMemsetAsync(flags, 0, 2 * NG * NM * sizeof(unsigned), stream);
  hipLaunchKernelGGL(rnn_recur, dim3(NG * NM), dim3(1024), 0, stream,
                     input_sig, rate0, i2h_w, i2h_b, h2h_w, h2h_b,
                     rate_all, exch, flags);
  hipLaunchKernelGGL(rnn_readout, dim3(256), dim3(256), 0, stream,
                     rate_all, h2o_w, h2o_b, h2o_ctx_w, h2o_ctx_b, out0, out1);
}

// Round 10
// 2871.705 us; speedup vs baseline: 1.6544x; 1.6544x over previous
//
#include <hip/hip_runtime.h>

constexpr int T  = 1024;
constexpr int B  = 32;
constexpr int I_ = 64;
constexpr int H  = 1024;
constexpr int OF = 64;
constexpr int OC = 8;
constexpr int NG = 16;   // groups (2 batches each)
constexpr int NM = 16;   // member WGs per group (64 rows each)
constexpr int CH  = 136; // per-lane contiguous k-chunk (1088/8)
constexpr int CHP = 140; // padded chunk stride (12*l8 mod 32 -> all banks)
constexpr int BSTR = 8 * CHP;  // 1120 words per batch buffer
constexpr long long OUT1_OFF = (long long)T * B * OF;
constexpr long long OUT2_OFF = (long long)T * B * (OF + OC);
constexpr int RING_U64 = NG * 2 * 2 * 1024;  // [g][slot][b][elem] = 512 KB

// Agent-scope relaxed ops: global_{load,store}_dwordx2 sc0 sc1 — bypass L1/L2,
// coherent at L3, fence-free. Proven medium (R2/R6/R8). sc0-only polling
// livelocks (R4/R5/R7) — never used.
__device__ __forceinline__ void st_agent_u64(unsigned long long* p,
                                             unsigned long long v) {
  __hip_atomic_store(p, v, __ATOMIC_RELAXED, __HIP_MEMORY_SCOPE_AGENT);
}
__device__ __forceinline__ unsigned long long
ld_agent_u64(const unsigned long long* p) {
  return __hip_atomic_load(p, __ATOMIC_RELAXED, __HIP_MEMORY_SCOPE_AGENT);
}

// ---------------------------------------------------------------------------
// Recurrence: 256 persistent WGs x 512 threads (1/CU).
// Group g = bid&15 owns batches {2g, 2g+1}; member m = bid>>4 owns rows
// [m*64, m*64+64). Thread (jrel=tid>>3, l8=tid&7): row j=m*64+jrel, k-chunk
// [l8*136, +136). Weights register-stationary (34 float4).
//
// Exchange: tagged u64 packets {u32 tag=t+1 | f32 val} in a 2-slot ring
// (slot=t&1). The data load IS the sync (one L3 RT, no counters/flags/drains).
// PING-PONG SCHEDULE gives every probe a compute-phase head start:
//   C0(t): compute batch0, store packets (tag t+1, slot t&1)
//   probe1: batch1's r_t  (tag t, slot (t-1)&1 — stored ONE FULL STEP ago)
//   barrier
//   C1(t): compute batch1, store packets
//   probe0: batch0's r_{t+1}-input = packets from C0(t) (~0.8us old)
//   barrier
// Liveness/lap-safety: a slot is overwritten (tag+2) only after the writer's
// own probes observed stores that PROGRAM-ORDER-FOLLOW every reader's
// completed probe of the old tag => an expected tag can never be skipped.
// Ring zeroed every call => stale tags (>=1) never match.
// ---------------------------------------------------------------------------
__global__ __launch_bounds__(512, 2) void rnn_recur(
    const float* __restrict__ input_sig, const float* __restrict__ rate0,
    const float* __restrict__ i2h_w, const float* __restrict__ i2h_b,
    const float* __restrict__ h2h_w, const float* __restrict__ h2h_b,
    float* __restrict__ rate_all, unsigned long long* __restrict__ ring)
{
  const int tid = threadIdx.x;
  const int bid = blockIdx.x;
  const int g   = bid & (NG - 1);
  const int m   = bid >> 4;
  const int l8  = tid & 7;
  const int jrel = tid >> 3;
  const int j   = m * 64 + jrel;
  const int bG  = g * 2;

  __shared__ float lds[2][BSTR];   // [batch][padded chunks], 9 KB

  // ---- register-stationary weights: 34 float4 = 136 fp32/thread
  float4 w4[34];
#pragma unroll
  for (int q = 0; q < 34; ++q) {
    const int k = l8 * CH + q * 4;
    w4[q] = (k < H) ? *(const float4*)(h2h_w + (long long)j * H + k)
                    : *(const float4*)(i2h_w + (long long)j * I_ + (k - H));
  }
  const float bsum = h2h_b[j] + i2h_b[j];
  const int posj = (j / CH) * CHP + (j % CH);

  // ---- init: r_{-1} = rate0 and x_0 for both batches (plain cached loads)
  {
    const int b = tid >> 8, u4 = tid & 255;
    const int k0 = u4 * 4, c = k0 / CH, off = k0 - c * CH;
    float4 v = *(const float4*)(rate0 + (long long)(bG + b) * H + k0);
    *(float4*)&lds[b][c * CHP + off] = v;
    if (tid < 32) {
      const int b2 = tid >> 4, iq = tid & 15;
      float4 u = *(const float4*)(input_sig + (long long)(bG + b2) * I_ + iq * 4);
      *(float4*)&lds[b2][7 * CHP + 72 + iq * 4] = u;
    }
  }
  __syncthreads();

  unsigned long long* ringG = ring + (long long)g * (2 * 2 * 1024);

  // compute one batch's step t: matvec + tanh + leaky, publish tagged packets
  auto phase = [&](int b, int t) {
    const float* Rb = &lds[b][0];
    float acc = 0.f;
#pragma unroll
    for (int q = 0; q < 34; ++q) {
      const float4 rv = *(const float4*)&Rb[l8 * CHP + q * 4];
      acc = fmaf(w4[q].x, rv.x, acc);
      acc = fmaf(w4[q].y, rv.y, acc);
      acc = fmaf(w4[q].z, rv.z, acc);
      acc = fmaf(w4[q].w, rv.w, acc);
    }
    acc += __shfl_xor(acc, 4, 64);
    acc += __shfl_xor(acc, 2, 64);
    acc += __shfl_xor(acc, 1, 64);
    if (l8 == 0) {
      const float pre  = acc + bsum;
      const float rold = Rb[posj];
      const float rnew = 0.9f * rold + 0.1f * tanhf(pre);
      const unsigned long long pkt =
          ((unsigned long long)(unsigned)(t + 1) << 32) |
          (unsigned long long)__float_as_uint(rnew);
      st_agent_u64(&ringG[((long long)((t & 1) * 2 + b) << 10) + j], pkt);
      rate_all[((long long)t * B + bG + b) * H + j] = rnew;  // plain cached
    }
  };

  // restage batch b's state (expect tag, from slot) + x_{xt} into LDS
  auto probe = [&](int b, unsigned tag, int slot, int xt) {
    float4 xv;
    const bool xs = (tid < 16);
    if (xs) {
      xv = *(const float4*)(input_sig + ((long long)xt * B + bG + b) * I_ + tid * 4);
    }
    const unsigned long long* p = &ringG[((long long)(slot * 2 + b) << 10) + 2 * tid];
    unsigned long long v0 = ld_agent_u64(p);
    unsigned long long v1 = ld_agent_u64(p + 1);
    while ((unsigned)(v0 >> 32) != tag || (unsigned)(v1 >> 32) != tag) {
      v0 = ld_agent_u64(p);
      v1 = ld_agent_u64(p + 1);
    }
    const int c = (2 * tid) / CH, off = 2 * tid - c * CH;
    *(float2*)&lds[b][c * CHP + off] = make_float2(
        __uint_as_float((unsigned)v0), __uint_as_float((unsigned)v1));
    if (xs) *(float4*)&lds[b][7 * CHP + 72 + tid * 4] = xv;
  };

  for (int t = 0; t < T; ++t) {
    // C0(t): uses lds[0] (= r_t(b0), staged by probe0 of step t-1 / init)
    phase(0, t);
    // probe1: r_t(b1) from C1(t-1) — one full step of head start
    if (t > 0) probe(1, (unsigned)t, (t - 1) & 1, t);
    __syncthreads();
    // C1(t): uses lds[1]
    phase(1, t);
    // probe0: r_{t+1}-input for C0(t+1) = packets from C0(t) (~0.8us old)
    if (t + 1 < T) probe(0, (unsigned)(t + 1), t & 1, t + 1);
    __syncthreads();
  }
}

// ---------------------------------------------------------------------------
// Readout: C[32768,72] = rate_all[32768,1024] x [h2o_w;h2o_ctx_w]^T + bias
// ---------------------------------------------------------------------------
__global__ __launch_bounds__(256) void rnn_readout(
    const float* __restrict__ rate_all,
    const float* __restrict__ h2o_w, const float* __restrict__ h2o_b,
    const float* __restrict__ h2o_ctx_w, const float* __restrict__ h2o_ctx_b,
    float* __restrict__ out0, float* __restrict__ out1)
{
  constexpr int RB = 128;
  constexpr int HC = 128;
  constexpr int SR = HC + 1;
  __shared__ float rl[RB * SR];
  __shared__ float wl[72 * SR];

  const int tid = threadIdx.x;
  const long long row0 = (long long)blockIdx.x * RB;
  const int rb = tid & 31, og = tid >> 5;

  float acc[4][9];
#pragma unroll
  for (int c = 0; c < 4; ++c)
#pragma unroll
    for (int i = 0; i < 9; ++i) acc[c][i] = 0.f;

  for (int hc = 0; hc < H / HC; ++hc) {
#pragma unroll
    for (int i = 0; i < 16; ++i) {
      const int q = i * 256 + tid;
      const int row = q >> 5, hq = q & 31;
      float4 v = *(const float4*)(rate_all + (row0 + row) * H + hc * HC + hq * 4);
      float* d = &rl[row * SR + hq * 4];
      d[0] = v.x; d[1] = v.y; d[2] = v.z; d[3] = v.w;
    }
#pragma unroll
    for (int i = 0; i < 9; ++i) {
      const int q = i * 256 + tid;
      const int o = q >> 5, hq = q & 31;
      const float* src = (o < OF) ? (h2o_w + (long long)o * H)
                                  : (h2o_ctx_w + (long long)(o - OF) * H);
      float4 v = *(const float4*)(src + hc * HC + hq * 4);
      float* d = &wl[o * SR + hq * 4];
      d[0] = v.x; d[1] = v.y; d[2] = v.z; d[3] = v.w;
    }
    __syncthreads();

#pragma unroll 4
    for (int h = 0; h < HC; ++h) {
      const float r0 = rl[(rb)      * SR + h];
      const float r1 = rl[(rb + 32) * SR + h];
      const float r2 = rl[(rb + 64) * SR + h];
      const float r3 = rl[(rb + 96) * SR + h];
#pragma unroll
      for (int i = 0; i < 9; ++i) {
        const float wv = wl[(og * 9 + i) * SR + h];
        acc[0][i] = fmaf(r0, wv, acc[0][i]);
        acc[1][i] = fmaf(r1, wv, acc[1][i]);
        acc[2][i] = fmaf(r2, wv, acc[2][i]);
        acc[3][i] = fmaf(r3, wv, acc[3][i]);
      }
    }
    __syncthreads();
  }

#pragma unroll
  for (int c = 0; c < 4; ++c) {
    const long long row = row0 + rb + 32 * c;
#pragma unroll
    for (int i = 0; i < 9; ++i) {
      const int o = og * 9 + i;
      if (o < OF) out0[row * OF + o] = acc[c][i] + h2o_b[o];
      else        out1[row * OC + (o - OF)] = acc[c][i] + h2o_ctx_b[o - OF];
    }
  }
}

extern "C" void kernel_launch(void* const* d_in, const int* in_sizes, int n_in,
                              void* d_out, int out_size, void* d_ws, size_t ws_size,
                              hipStream_t stream) {
  (void)in_sizes; (void)n_in; (void)d_ws; (void)ws_size; (void)out_size;
  const float* input_sig = (const float*)d_in[0];
  const float* rate0     = (const float*)d_in[1];
  const float* i2h_w     = (const float*)d_in[2];
  const float* i2h_b     = (const float*)d_in[3];
  const float* h2h_w     = (const float*)d_in[4];
  const float* h2h_b     = (const float*)d_in[5];
  const float* h2o_w     = (const float*)d_in[6];
  const float* h2o_b     = (const float*)d_in[7];
  const float* h2o_ctx_w = (const float*)d_in[8];
  const float* h2o_ctx_b = (const float*)d_in[9];

  float* out      = (float*)d_out;
  float* out0     = out;
  float* out1     = out + OUT1_OFF;
  float* rate_all = out + OUT2_OFF;
  // Tagged 2-slot ring in the first 512 KB of out0 (overwritten by readout).
  unsigned long long* ring = (unsigned long long*)d_out;

  // Zero the ring EVERY call: expected tags are >=1, so zero never matches;
  // stale tags from a previous call/graph-replay would otherwise alias.
  hipMemsetAsync(ring, 0, (size_t)RING_U64 * 8, stream);
  hipLaunchKernelGGL(rnn_recur, dim3(NG * NM), dim3(512), 0, stream,
                     input_sig, rate0, i2h_w, i2h_b, h2h_w, h2h_b,
                     rate_all, ring);
  hipLaunchKernelGGL(rnn_readout, dim3(256), dim3(256), 0, stream,
                     rate_all, h2o_w, h2o_b, h2o_ctx_w, h2o_ctx_b, out0, out1);
}

// Round 11
// 2506.647 us; speedup vs baseline: 1.8953x; 1.1456x over previous
//
#include <hip/hip_runtime.h>

typedef float v2f __attribute__((ext_vector_type(2)));
typedef float v4f __attribute__((ext_vector_type(4)));

constexpr int T  = 1024;
constexpr int B  = 32;
constexpr int I_ = 64;
constexpr int H  = 1024;
constexpr int OF = 64;
constexpr int OC = 8;
constexpr int NG = 16;   // groups (2 batches each)
constexpr int NM = 16;   // member WGs per group (64 rows each)
constexpr int CH  = 136; // per-lane contiguous k-chunk (1088/8)
constexpr int CHP = 140; // padded chunk stride (12*l8 mod 32 -> all banks)
constexpr int BSTR = 8 * CHP;
constexpr long long OUT1_OFF = (long long)T * B * OF;
constexpr long long OUT2_OFF = (long long)T * B * (OF + OC);
constexpr int RING_U64 = NG * 2 * 2 * 1024;  // [g][slot][b][elem] = 512 KB

// Agent-scope relaxed ops: global_{load,store} sc0 sc1 — bypass L1/L2,
// coherent at L3, fence-free. Proven (R2/R6/R8/R10). sc0-only polling
// livelocks (R4/R5/R7) — never used.
__device__ __forceinline__ void st_agent_u64(unsigned long long* p,
                                             unsigned long long v) {
  __hip_atomic_store(p, v, __ATOMIC_RELAXED, __HIP_MEMORY_SCOPE_AGENT);
}
__device__ __forceinline__ unsigned long long
ld_agent_u64(const unsigned long long* p) {
  return __hip_atomic_load(p, __ATOMIC_RELAXED, __HIP_MEMORY_SCOPE_AGENT);
}

// ---------------------------------------------------------------------------
// Recurrence: 256 persistent WGs x 512 threads (1/CU).
// Group g = bid&15 owns batches {2g, 2g+1}; member m = bid>>4 owns rows
// [m*64, m*64+64). Thread (jrel=tid>>3, l8=tid&7): row j=m*64+jrel, k-chunk
// [l8*136, +136). Weights register-stationary as 68 float2 (pk-FMA operands).
//
// Exchange: tagged u64 packets {u32 tag=t+1 | f32 val}, 2-slot ring
// (slot=t&1); the data load IS the sync. PING-PONG + EARLY ISSUE:
//   issue L1 loads (b1 r_t, stored a FULL STEP ago)  + x_t(b1)
//   C0(t): pk-FMA matvec b0, store packets (tag t+1, slot t&1)
//   check L1 tags (loads flew under C0) -> commit lds[1]; re-poll if stale
//   barrier
//   issue L0 loads (b0 r_{t+1}-inputs = C0(t) packets, ~stored during C0)
//   C1(t): matvec b1, store packets
//   check L0 -> commit lds[0]
//   barrier
// Tag-check POSITIONS are identical to R10, so R10's liveness/lap-safety
// induction carries over verbatim (any slot overwrite at tag+2 is gated,
// through the all-rows probe coverage + in-WG barriers, on every member's
// completed check of the old tag). Stale early reads just fail the check and
// enter the proven re-poll loop. Ring zeroed every call (tags >= 1).
// ---------------------------------------------------------------------------
__global__ __launch_bounds__(512, 2) void rnn_recur(
    const float* __restrict__ input_sig, const float* __restrict__ rate0,
    const float* __restrict__ i2h_w, const float* __restrict__ i2h_b,
    const float* __restrict__ h2h_w, const float* __restrict__ h2h_b,
    float* __restrict__ rate_all, unsigned long long* __restrict__ ring)
{
  const int tid = threadIdx.x;
  const int bid = blockIdx.x;
  const int g   = bid & (NG - 1);
  const int m   = bid >> 4;
  const int l8  = tid & 7;
  const int jrel = tid >> 3;
  const int j   = m * 64 + jrel;
  const int bG  = g * 2;

  __shared__ float lds[2][BSTR];   // [batch][padded chunks]

  // ---- register-stationary weights: 68 float2 = 136 fp32/thread
  v2f w2[68];
#pragma unroll
  for (int q = 0; q < 68; ++q) {
    const int k = l8 * CH + q * 2;
    w2[q] = (k < H) ? *(const v2f*)(h2h_w + (long long)j * H + k)
                    : *(const v2f*)(i2h_w + (long long)j * I_ + (k - H));
  }
  const float bsum = h2h_b[j] + i2h_b[j];
  const int posj = (j / CH) * CHP + (j % CH);

  // ---- init: r_{-1} = rate0 and x_0 for both batches (plain cached loads)
  {
    const int b = tid >> 8, u4 = tid & 255;
    const int k0 = u4 * 4, c = k0 / CH, off = k0 - c * CH;
    float4 v = *(const float4*)(rate0 + (long long)(bG + b) * H + k0);
    *(float4*)&lds[b][c * CHP + off] = v;
    if (tid < 32) {
      const int b2 = tid >> 4, iq = tid & 15;
      float4 u = *(const float4*)(input_sig + (long long)(bG + b2) * I_ + iq * 4);
      *(float4*)&lds[b2][7 * CHP + 72 + iq * 4] = u;
    }
  }
  __syncthreads();

  unsigned long long* ringG = ring + (long long)g * (2 * 2 * 1024);
  const int c_  = (2 * tid) / CH;
  const int off_ = 2 * tid - c_ * CH;

  // compute one batch's step t: pk-FMA matvec + tanh + leaky, publish packets
  auto phase = [&](int b, int t) {
    const float* Rb = &lds[b][0];
    v2f acc2 = {0.f, 0.f};
#pragma unroll
    for (int q = 0; q < 34; ++q) {
      const v4f rv = *(const v4f*)&Rb[l8 * CHP + q * 4];
      const v2f rlo = __builtin_shufflevector(rv, rv, 0, 1);
      const v2f rhi = __builtin_shufflevector(rv, rv, 2, 3);
      acc2 = __builtin_elementwise_fma(w2[2 * q],     rlo, acc2);
      acc2 = __builtin_elementwise_fma(w2[2 * q + 1], rhi, acc2);
    }
    float acc = acc2.x + acc2.y;
    acc += __shfl_xor(acc, 4, 64);
    acc += __shfl_xor(acc, 2, 64);
    acc += __shfl_xor(acc, 1, 64);
    if (l8 == 0) {
      const float pre  = acc + bsum;
      const float rold = Rb[posj];
      const float rnew = 0.9f * rold + 0.1f * tanhf(pre);
      const unsigned long long pkt =
          ((unsigned long long)(unsigned)(t + 1) << 32) |
          (unsigned long long)__float_as_uint(rnew);
      st_agent_u64(&ringG[((long long)((t & 1) * 2 + b) << 10) + j], pkt);
      rate_all[((long long)t * B + bG + b) * H + j] = rnew;  // plain cached
    }
  };

  for (int t = 0; t < T; ++t) {
    // ---- early-issue: b1's r_t (slot (t-1)&1, tag t) + x_t(b1)
    unsigned long long v10 = 0, v11 = 0;
    float4 xv1;
    const bool have1 = (t > 0);
    const unsigned long long* p1 =
        &ringG[((long long)((((t - 1) & 1) * 2) + 1) << 10) + 2 * tid];
    if (have1) {
      v10 = ld_agent_u64(p1);
      v11 = ld_agent_u64(p1 + 1);
      if (tid < 16) {
        xv1 = *(const float4*)(input_sig +
            ((long long)t * B + bG + 1) * I_ + tid * 4);
      }
    }

    phase(0, t);   // C0(t): loads above fly under this

    if (have1) {
      const unsigned tag = (unsigned)t;
      while ((unsigned)(v10 >> 32) != tag || (unsigned)(v11 >> 32) != tag) {
        v10 = ld_agent_u64(p1);
        v11 = ld_agent_u64(p1 + 1);
      }
      *(float2*)&lds[1][c_ * CHP + off_] = make_float2(
          __uint_as_float((unsigned)v10), __uint_as_float((unsigned)v11));
      if (tid < 16) *(float4*)&lds[1][7 * CHP + 72 + tid * 4] = xv1;
    }
    __syncthreads();

    // ---- early-issue: b0's r_{t+1} inputs (slot t&1, tag t+1) + x_{t+1}(b0)
    unsigned long long v00 = 0, v01 = 0;
    float4 xv0;
    const bool have0 = (t + 1 < T);
    const unsigned long long* p0 =
        &ringG[((long long)((t & 1) * 2) << 10) + 2 * tid];
    if (have0) {
      v00 = ld_agent_u64(p0);
      v01 = ld_agent_u64(p0 + 1);
      if (tid < 16) {
        xv0 = *(const float4*)(input_sig +
            ((long long)(t + 1) * B + bG) * I_ + tid * 4);
      }
    }

    phase(1, t);   // C1(t)

    if (have0) {
      const unsigned tag = (unsigned)(t + 1);
      while ((unsigned)(v00 >> 32) != tag || (unsigned)(v01 >> 32) != tag) {
        v00 = ld_agent_u64(p0);
        v01 = ld_agent_u64(p0 + 1);
      }
      *(float2*)&lds[0][c_ * CHP + off_] = make_float2(
          __uint_as_float((unsigned)v00), __uint_as_float((unsigned)v01));
      if (tid < 16) *(float4*)&lds[0][7 * CHP + 72 + tid * 4] = xv0;
    }
    __syncthreads();
  }
}

// ---------------------------------------------------------------------------
// Readout: C[32768,72] = rate_all[32768,1024] x [h2o_w;h2o_ctx_w]^T + bias
// ---------------------------------------------------------------------------
__global__ __launch_bounds__(256) void rnn_readout(
    const float* __restrict__ rate_all,
    const float* __restrict__ h2o_w, const float* __restrict__ h2o_b,
    const float* __restrict__ h2o_ctx_w, const float* __restrict__ h2o_ctx_b,
    float* __restrict__ out0, float* __restrict__ out1)
{
  constexpr int RB = 128;
  constexpr int HC = 128;
  constexpr int SR = HC + 1;
  __shared__ float rl[RB * SR];
  __shared__ float wl[72 * SR];

  const int tid = threadIdx.x;
  const long long row0 = (long long)blockIdx.x * RB;
  const int rb = tid & 31, og = tid >> 5;

  float acc[4][9];
#pragma unroll
  for (int c = 0; c < 4; ++c)
#pragma unroll
    for (int i = 0; i < 9; ++i) acc[c][i] = 0.f;

  for (int hc = 0; hc < H / HC; ++hc) {
#pragma unroll
    for (int i = 0; i < 16; ++i) {
      const int q = i * 256 + tid;
      const int row = q >> 5, hq = q & 31;
      float4 v = *(const float4*)(rate_all + (row0 + row) * H + hc * HC + hq * 4);
      float* d = &rl[row * SR + hq * 4];
      d[0] = v.x; d[1] = v.y; d[2] = v.z; d[3] = v.w;
    }
#pragma unroll
    for (int i = 0; i < 9; ++i) {
      const int q = i * 256 + tid;
      const int o = q >> 5, hq = q & 31;
      const float* src = (o < OF) ? (h2o_w + (long long)o * H)
                                  : (h2o_ctx_w + (long long)(o - OF) * H);
      float4 v = *(const float4*)(src + hc * HC + hq * 4);
      float* d = &wl[o * SR + hq * 4];
      d[0] = v.x; d[1] = v.y; d[2] = v.z; d[3] = v.w;
    }
    __syncthreads();

#pragma unroll 4
    for (int h = 0; h < HC; ++h) {
      const float r0 = rl[(rb)      * SR + h];
      const float r1 = rl[(rb + 32) * SR + h];
      const float r2 = rl[(rb + 64) * SR + h];
      const float r3 = rl[(rb + 96) * SR + h];
#pragma unroll
      for (int i = 0; i < 9; ++i) {
        const float wv = wl[(og * 9 + i) * SR + h];
        acc[0][i] = fmaf(r0, wv, acc[0][i]);
        acc[1][i] = fmaf(r1, wv, acc[1][i]);
        acc[2][i] = fmaf(r2, wv, acc[2][i]);
        acc[3][i] = fmaf(r3, wv, acc[3][i]);
      }
    }
    __syncthreads();
  }

#pragma unroll
  for (int c = 0; c < 4; ++c) {
    const long long row = row0 + rb + 32 * c;
#pragma unroll
    for (int i = 0; i < 9; ++i) {
      const int o = og * 9 + i;
      if (o < OF) out0[row * OF + o] = acc[c][i] + h2o_b[o];
      else        out1[row * OC + (o - OF)] = acc[c][i] + h2o_ctx_b[o - OF];
    }
  }
}

extern "C" void kernel_launch(void* const* d_in, const int* in_sizes, int n_in,
                              void* d_out, int out_size, void* d_ws, size_t ws_size,
                              hipStream_t stream) {
  (void)in_sizes; (void)n_in; (void)d_ws; (void)ws_size; (void)out_size;
  const float* input_sig = (const float*)d_in[0];
  const float* rate0     = (const float*)d_in[1];
  const float* i2h_w     = (const float*)d_in[2];
  const float* i2h_b     = (const float*)d_in[3];
  const float* h2h_w     = (const float*)d_in[4];
  const float* h2h_b     = (const float*)d_in[5];
  const float* h2o_w     = (const float*)d_in[6];
  const float* h2o_b     = (const float*)d_in[7];
  const float* h2o_ctx_w = (const float*)d_in[8];
  const float* h2o_ctx_b = (const float*)d_in[9];

  float* out      = (float*)d_out;
  float* out0     = out;
  float* out1     = out + OUT1_OFF;
  float* rate_all = out + OUT2_OFF;
  // Tagged 2-slot ring in the first 512 KB of out0 (overwritten by readout).
  unsigned long long* ring = (unsigned long long*)d_out;

  // Zero the ring EVERY call: expected tags are >=1, so zero never matches;
  // stale tags from a previous call/graph-replay would otherwise alias.
  hipMemsetAsync(ring, 0, (size_t)RING_U64 * 8, stream);
  hipLaunchKernelGGL(rnn_recur, dim3(NG * NM), dim3(512), 0, stream,
                     input_sig, rate0, i2h_w, i2h_b, h2h_w, h2h_b,
                     rate_all, ring);
  hipLaunchKernelGGL(rnn_readout, dim3(256), dim3(256), 0, stream,
                     rate_all, h2o_w, h2o_b, h2o_ctx_w, h2o_ctx_b, out0, out1);
}